// Round 12
// baseline (1015.742 us; speedup 1.0000x reference)
//
#include <hip/hip_runtime.h>
#include <hip/hip_bf16.h>

// BinaryLinear: C[M,N] = (x[M,K] @ sign(W)[N,K]^T) * scale + bias
// M=8192 K=4096 N=16384 fp32. Round 12: i8 path (W=+-1 exact, x global-
// absmax/127 quant, i32 accum exact; absmax 5.0 measured). GEMM: 256x256,
// 8 waves (2x4, wave 128x64), mfma_i32_32x32x32_i8, BK=128 dbuf, BUT the
// LDS layout reverts to the measured-zero-conflict family: 64-B rows in
// four half-regions {A0,A1,B0,B1} per buffer with chunk-XOR (row>>1)&3
// (R10 geometry). k-step s: region s>>1, addr XOR (s&1)<<5.

typedef __attribute__((ext_vector_type(4))) float f32x4;
typedef __attribute__((ext_vector_type(4))) int i32x4;
typedef __attribute__((ext_vector_type(16))) int i32x16;
typedef __attribute__((ext_vector_type(8))) short s16x8;
typedef __attribute__((ext_vector_type(4))) unsigned int u32x4;

#define AS1(p) ((const __attribute__((address_space(1))) void*)(p))
#define AS3(p) ((__attribute__((address_space(3))) void*)(p))

// ---------------- preprocessing (verified R10/R11) ----------------

__global__ void zero_scalar(unsigned* u) {
  if (threadIdx.x == 0 && blockIdx.x == 0) u[0] = 0u;
}

__global__ void __launch_bounds__(256) absmax_f32(const float* __restrict__ in,
                                                  unsigned* __restrict__ out,
                                                  int n8) {
  int i = blockIdx.x * 256 + threadIdx.x;
  const int stride = gridDim.x * 256;
  float m = 0.0f;
  for (; i < n8; i += stride) {
    const f32x4* p = (const f32x4*)in + (size_t)i * 2;
    f32x4 v0 = p[0], v1 = p[1];
#pragma unroll
    for (int j = 0; j < 4; ++j) {
      m = fmaxf(m, fabsf(v0[j]));
      m = fmaxf(m, fabsf(v1[j]));
    }
  }
#pragma unroll
  for (int mask = 32; mask >= 1; mask >>= 1)
    m = fmaxf(m, __shfl_xor(m, mask, 64));
  if ((threadIdx.x & 63) == 0)
    atomicMax(out, __float_as_uint(m));  // positive floats: bit-order == value-order
}

__global__ void __launch_bounds__(256) quant_x(const float* __restrict__ in,
                                               signed char* __restrict__ out,
                                               const unsigned* __restrict__ mb,
                                               int n8) {
  const float s_inv = 127.0f / __uint_as_float(mb[0]);
  int i = blockIdx.x * 256 + threadIdx.x;
  const int stride = gridDim.x * 256;
  for (; i < n8; i += stride) {
    const f32x4* p = (const f32x4*)in + (size_t)i * 2;
    f32x4 v0 = p[0], v1 = p[1];
    unsigned b[8];
#pragma unroll
    for (int j = 0; j < 4; ++j) {
      b[j] = (unsigned)((int)rintf(fminf(fmaxf(v0[j] * s_inv, -127.f), 127.f))) & 255u;
      b[4 + j] = (unsigned)((int)rintf(fminf(fmaxf(v1[j] * s_inv, -127.f), 127.f))) & 255u;
    }
    uint2 o;
    o.x = b[0] | (b[1] << 8) | (b[2] << 16) | (b[3] << 24);
    o.y = b[4] | (b[5] << 8) | (b[6] << 16) | (b[7] << 24);
    *(uint2*)(out + (size_t)i * 8) = o;
  }
}

__global__ void __launch_bounds__(256) bin_w_i8(const unsigned* __restrict__ in,
                                                signed char* __restrict__ out,
                                                int n8) {
  int i = blockIdx.x * 256 + threadIdx.x;
  const int stride = gridDim.x * 256;
  for (; i < n8; i += stride) {
    const u32x4* p = (const u32x4*)in + (size_t)i * 2;
    u32x4 v0 = p[0], v1 = p[1];
    unsigned b[8];
#pragma unroll
    for (int j = 0; j < 4; ++j) {  // sign(0)=+1: byte = w<0 ? 0xFF : 0x01
      b[j] = 1u | ((unsigned)(((int)v0[j]) >> 31) & 0xFEu);
      b[4 + j] = 1u | ((unsigned)(((int)v1[j]) >> 31) & 0xFEu);
    }
    uint2 o;
    o.x = b[0] | (b[1] << 8) | (b[2] << 16) | (b[3] << 24);
    o.y = b[4] | (b[5] << 8) | (b[6] << 16) | (b[7] << 24);
    *(uint2*)(out + (size_t)i * 8) = o;
  }
}

// ---------------- i8 GEMM, BK=128, 32x32x32, half-region LDS ----------------
// LDS (128 KiB): buf{0,1} x regions {A0@0, A1@16K, B0@32K, B1@48K}, each
// 16 KB = 256 rows x 64 B (one operand x one K-half of 64 i8).
//   row byte = row*64 + ((c4 ^ ((row>>1)&3))*16, c4 = logical 16B chunk 0..3.
//   [This row-geometry + swizzle measured 0 conflicts in R2/R3/R7/R10.]
// Frag (32x32x32, k-step s=0..3): region h=s>>1; row = base + l31;
//   logical c4 = ((s&1)<<1)|l5 -> stored = l5 ^ ((l31>>1)&3) XOR (s&1)<<1;
//   addr = (rd + sub) ^ ((s&1)<<5), rd per-lane constant.
// Stage (8 x global_load_lds w=16/iter): dest region + g*8192 + tid*16
//   (row g*128+(tid>>2), stored chunk tid&3); source logical chunk
//   kc2 = (tid&3)^((tid>>3)&3), col = koff + h*64 + kc2*16.
// Iter t: [stage tile t+1 (8 loads)] [4 k-steps x {6 ds_read_b128, 8 MFMA}]
//   [vmcnt(0): retires t+1's loads, issued a full iteration (~5-6k cyc)
//   earlier] [barrier].

#define WAITV0() asm volatile("s_waitcnt vmcnt(0)" ::: "memory")
#define BAR()    __builtin_amdgcn_s_barrier()
#define LDSB ((const char*)lds)

#define STAGE_I8(bufo, koff)                                                   \
  do {                                                                         \
    _Pragma("unroll") for (int h = 0; h < 2; ++h)                              \
        _Pragma("unroll") for (int g = 0; g < 2; ++g)                          \
            __builtin_amdgcn_global_load_lds(                                  \
                AS1(sA + (long)g * 128 * Kb + (koff) + h * 64),                \
                AS3((char*)lds + (bufo) + h * 16384 + g * 8192 + tid * 16),    \
                16, 0, 0);                                                     \
    _Pragma("unroll") for (int h = 0; h < 2; ++h)                              \
        _Pragma("unroll") for (int g = 0; g < 2; ++g)                          \
            __builtin_amdgcn_global_load_lds(                                  \
                AS1(sB + (long)g * 128 * Kb + (koff) + h * 64),                \
                AS3((char*)lds + (bufo) + 32768 + h * 16384 + g * 8192 +       \
                    tid * 16),                                                 \
                16, 0, 0);                                                     \
  } while (0)

__global__ void __launch_bounds__(512, 2)
gemm_i8(const signed char* __restrict__ A, const signed char* __restrict__ B,
        const float* __restrict__ scale, const float* __restrict__ bias,
        const unsigned* __restrict__ mb, float* __restrict__ C,
        const int M, const int N, const int K) {
  __shared__ signed char lds[131072];  // 128 KiB
  const int tid = threadIdx.x;
  const int lane = tid & 63;
  const int wv = tid >> 6;   // 0..7
  const int wm = wv >> 2;    // 0..1
  const int wn = wv & 3;     // 0..3
  const int l31 = lane & 31, l5 = lane >> 5;

  // XCD-aware swizzle (bijective: nwg % 8 == 0)
  const int mt = M >> 8, nt = N >> 8;
  const int nwg = mt * nt;
  const int orig = blockIdx.x;
  const int wg = (nwg & 7) ? orig : ((orig & 7) * (nwg >> 3) + (orig >> 3));
  const int bm = wg % mt;
  const int bn = wg / mt;
  const int rA0 = bm * 256, rB0 = bn * 256;

  // ds_read bases (region-relative, 64-B rows, verified swizzle family)
  const int chb = (l5 ^ ((l31 >> 1) & 3)) * 16;
  const int rdA = (wm * 128 + l31) * 64 + chb;             // within A-half region
  const int rdB = 32768 + (wn * 64 + l31) * 64 + chb;      // within B-half region

  // stage source base (inverse-swizzled; row = tid>>2, kc2 per R10 formula)
  const int kc2 = (tid & 3) ^ ((tid >> 3) & 3);
  const long Kb = (long)K;  // bytes per row (i8)
  const signed char* sA = A + (long)(rA0 + (tid >> 2)) * Kb + kc2 * 16;
  const signed char* sB = B + (long)(rB0 + (tid >> 2)) * Kb + kc2 * 16;

  i32x16 acc[4][2] = {};
  const int NT = K >> 7;  // 32

  // prologue: tile 0 -> buf0
  STAGE_I8(0, 0);
  WAITV0();
  BAR();

  for (int t = 0; t < NT; ++t) {
    const int bufR = (t & 1) << 16;
    const int bufW = bufR ^ 65536;
    int tt = t + 1; if (tt == NT) tt = 0;  // wrapped final stage (harmless)
    STAGE_I8(bufW, (long)tt * 128);

#pragma unroll
    for (int s = 0; s < 4; ++s) {
      const int hofs = (s >> 1) * 16384;  // K-half region
      const int sx = (s & 1) << 5;        // chunk-pair XOR within 64-B row
      i32x4 a[4], b[2];
#pragma unroll
      for (int nj = 0; nj < 2; ++nj)
        b[nj] = *(const i32x4*)(LDSB + bufR + hofs + ((rdB + nj * 2048) ^ sx));
#pragma unroll
      for (int mi = 0; mi < 4; ++mi)
        a[mi] = *(const i32x4*)(LDSB + bufR + hofs + ((rdA + mi * 2048) ^ sx));
#pragma unroll
      for (int mi = 0; mi < 4; ++mi)
#pragma unroll
        for (int nj = 0; nj < 2; ++nj)
          acc[mi][nj] = __builtin_amdgcn_mfma_i32_32x32x32_i8(
              a[mi], b[nj], acc[mi][nj], 0, 0, 0);
    }

    WAITV0();  // retires tile t+1's 8 loads (issued a full iteration ago)
    BAR();     // publish buf[t+1]
  }

  // epilogue: C = acc * (maxabs/127 * scale) + bias
  // 32x32 C/D (verified R5/R11): col=lane&31, row=(r&3)+8*(r>>2)+4*(lane>>5)
  const float sf = (__uint_as_float(mb[0]) / 127.0f) * scale[0];
  const int n0 = rB0 + wn * 64 + l31;
  float bb[2];
  bb[0] = bias[n0];
  bb[1] = bias[n0 + 32];
  const int m0 = rA0 + wm * 128 + 4 * l5;
#pragma unroll
  for (int mi = 0; mi < 4; ++mi) {
#pragma unroll
    for (int nj = 0; nj < 2; ++nj) {
#pragma unroll
      for (int r = 0; r < 16; ++r) {
        const int row = m0 + mi * 32 + (r & 3) + 8 * (r >> 2);
        C[(size_t)row * N + n0 + nj * 32] = (float)acc[mi][nj][r] * sf + bb[nj];
      }
    }
  }
}

// ---------------- no-workspace fallback (bf16 MFMA, in-kernel convert) ----
__device__ __forceinline__ unsigned short f2bf(float f) {
  unsigned u = __float_as_uint(f);
  u += 0x7FFFu + ((u >> 16) & 1u);
  return (unsigned short)(u >> 16);
}

__global__ void __launch_bounds__(256, 2)
gemm_fallback(const float* __restrict__ Ap, const float* __restrict__ Bp,
              const float* __restrict__ scale, const float* __restrict__ bias,
              float* __restrict__ C, const int M, const int N, const int K) {
  __shared__ unsigned short As[128 * 64];
  __shared__ unsigned short Bs[128 * 64];
  const int tid = threadIdx.x;
  const int lane = tid & 63;
  const int wv = tid >> 6;
  const int wm = wv >> 1, wn = wv & 1;
  const int bn = blockIdx.x, bm = blockIdx.y;
  const int lr = lane & 15, lk = lane >> 4;
  f32x4 acc[4][4] = {};
  const int rA0 = bm * 128, rB0 = bn * 128;

  for (int k0 = 0; k0 < K; k0 += 64) {
#pragma unroll
    for (int i = 0; i < 4; ++i) {
      const int c = i * 256 + tid;
      const int row = c >> 3, kc = c & 7;
      const f32x4* srcA = (const f32x4*)(Ap + (size_t)(rA0 + row) * K + (k0 + kc * 8));
      f32x4 v0 = srcA[0], v1 = srcA[1];
      s16x8 o;
      o[0] = (short)f2bf(v0[0]); o[1] = (short)f2bf(v0[1]);
      o[2] = (short)f2bf(v0[2]); o[3] = (short)f2bf(v0[3]);
      o[4] = (short)f2bf(v1[0]); o[5] = (short)f2bf(v1[1]);
      o[6] = (short)f2bf(v1[2]); o[7] = (short)f2bf(v1[3]);
      *(s16x8*)&As[(row * 8 + (kc ^ (row & 7))) * 8] = o;
      const u32x4* srcB =
          (const u32x4*)(Bp + (size_t)(rB0 + row) * K + (k0 + kc * 8));
      u32x4 w0 = srcB[0], w1 = srcB[1];
      s16x8 ob;
      ob[0] = (short)(0x3F80u | ((w0[0] >> 16) & 0x8000u));
      ob[1] = (short)(0x3F80u | ((w0[1] >> 16) & 0x8000u));
      ob[2] = (short)(0x3F80u | ((w0[2] >> 16) & 0x8000u));
      ob[3] = (short)(0x3F80u | ((w0[3] >> 16) & 0x8000u));
      ob[4] = (short)(0x3F80u | ((w1[0] >> 16) & 0x8000u));
      ob[5] = (short)(0x3F80u | ((w1[1] >> 16) & 0x8000u));
      ob[6] = (short)(0x3F80u | ((w1[2] >> 16) & 0x8000u));
      ob[7] = (short)(0x3F80u | ((w1[3] >> 16) & 0x8000u));
      *(s16x8*)&Bs[(row * 8 + (kc ^ (row & 7))) * 8] = ob;
    }
    __syncthreads();
#pragma unroll
    for (int ks = 0; ks < 2; ++ks) {
      s16x8 a[4], b[4];
#pragma unroll
      for (int mi = 0; mi < 4; ++mi) {
        const int row = wm * 64 + mi * 16 + lr;
        const int kc = ks * 4 + lk;
        a[mi] = *(const s16x8*)&As[(row * 8 + (kc ^ (row & 7))) * 8];
      }
#pragma unroll
      for (int ni = 0; ni < 4; ++ni) {
        const int row = wn * 64 + ni * 16 + lr;
        const int kc = ks * 4 + lk;
        b[ni] = *(const s16x8*)&Bs[(row * 8 + (kc ^ (row & 7))) * 8];
      }
#pragma unroll
      for (int mi = 0; mi < 4; ++mi)
#pragma unroll
        for (int ni = 0; ni < 4; ++ni)
          acc[mi][ni] = __builtin_amdgcn_mfma_f32_16x16x32_bf16(a[mi], b[ni],
                                                               acc[mi][ni], 0, 0, 0);
    }
    __syncthreads();
  }

  const float s = scale[0];
  const int n0 = rB0 + wn * 64 + lr;
  const int m0 = rA0 + wm * 64 + lk * 4;
  float bb[4];
#pragma unroll
  for (int ni = 0; ni < 4; ++ni) bb[ni] = bias[n0 + ni * 16];
#pragma unroll
  for (int mi = 0; mi < 4; ++mi) {
#pragma unroll
    for (int r = 0; r < 4; ++r) {
      float* crow = C + (size_t)(m0 + mi * 16 + r) * N + n0;
#pragma unroll
      for (int ni = 0; ni < 4; ++ni)
        crow[ni * 16] = acc[mi][ni][r] * s + bb[ni];
    }
  }
}

extern "C" void kernel_launch(void* const* d_in, const int* in_sizes, int n_in,
                              void* d_out, int out_size, void* d_ws, size_t ws_size,
                              hipStream_t stream) {
  const float* x = (const float*)d_in[0];
  const float* w = (const float*)d_in[1];
  const float* scale = (const float*)d_in[2];
  const float* bias = (const float*)d_in[3];
  float* out = (float*)d_out;

  const int K = 4096;
  const int M = in_sizes[0] / K;  // 8192
  const int N = in_sizes[3];      // 16384

  const size_t MK = (size_t)M * K, NK = (size_t)N * K;
  const size_t need = 256 + MK + NK;  // scalar + x_i8 + w_i8 (~96 MB)

  if (ws_size >= need && (M % 256) == 0 && (N % 256) == 0 && (K % 128) == 0 &&
      (K / 128) >= 2) {
    unsigned* mb = (unsigned*)d_ws;
    signed char* xq = (signed char*)d_ws + 256;
    signed char* wq = (signed char*)d_ws + 256 + MK;
    zero_scalar<<<1, 64, 0, stream>>>(mb);
    absmax_f32<<<2048, 256, 0, stream>>>(x, mb, (int)(MK / 8));
    quant_x<<<2048, 256, 0, stream>>>(x, xq, mb, (int)(MK / 8));
    bin_w_i8<<<2048, 256, 0, stream>>>((const unsigned*)w, wq, (int)(NK / 8));
    gemm_i8<<<dim3((M / 256) * (N / 256)), 512, 0, stream>>>(
        xq, wq, scale, bias, mb, out, M, N, K);
  } else {
    gemm_fallback<<<dim3(N / 128, M / 128), 256, 0, stream>>>(
        x, w, scale, bias, out, M, N, K);
  }
}

// Round 13
// 754.382 us; speedup vs baseline: 1.3465x; 1.3465x over previous
//
#include <hip/hip_runtime.h>
#include <hip/hip_bf16.h>

// BinaryLinear: C[M,N] = (x[M,K] @ sign(W)[N,K]^T) * scale + bias
// M=8192 K=4096 N=16384 fp32. Round 13: GEMM restored VERBATIM to R11's
// best-measured config (655 us: 256x256, 8 waves, mfma_i32_32x32x32_i8,
// BK=128 dbuf, 128-B-row LDS w/ ch^=row&7 swizzle, full-iter vmcnt lead).
// Preprocessing restructured: PER-ROW x quantization (one wave per row,
// shfl-reduce absmax + quantize in one kernel; no atomics, no zero pass)
// -> 2 kernels instead of 4, ~120 us less. Epilogue: acc * srow[m]*scale/127.

typedef __attribute__((ext_vector_type(4))) float f32x4;
typedef __attribute__((ext_vector_type(4))) int i32x4;
typedef __attribute__((ext_vector_type(16))) int i32x16;
typedef __attribute__((ext_vector_type(8))) short s16x8;
typedef __attribute__((ext_vector_type(4))) unsigned int u32x4;

#define AS1(p) ((const __attribute__((address_space(1))) void*)(p))
#define AS3(p) ((__attribute__((address_space(3))) void*)(p))

// ---------------- preprocessing ----------------
// One wave per x-row: pass 1 absmax (shfl reduce), pass 2 quantize
// (row is 16 KB -> second read hits L1/L2). srow[r] = row absmax.

__global__ void __launch_bounds__(256) quant_rows(const float* __restrict__ x,
                                                  signed char* __restrict__ xq,
                                                  float* __restrict__ srow,
                                                  int M, int K) {
  const int lane = threadIdx.x & 63;
  const int wid = blockIdx.x * 4 + (threadIdx.x >> 6);
  const int nw = gridDim.x * 4;
  for (int r = wid; r < M; r += nw) {
    const float* row = x + (size_t)r * K;
    float m = 0.f;
    for (int k = lane * 8; k < K; k += 512) {
      const f32x4* p = (const f32x4*)(row + k);
      f32x4 v0 = p[0], v1 = p[1];
#pragma unroll
      for (int j = 0; j < 4; ++j) {
        m = fmaxf(m, fabsf(v0[j]));
        m = fmaxf(m, fabsf(v1[j]));
      }
    }
#pragma unroll
    for (int mask = 32; mask >= 1; mask >>= 1)
      m = fmaxf(m, __shfl_xor(m, mask, 64));
    const float si = (m > 0.f) ? (127.0f / m) : 0.f;
    if (lane == 0) srow[r] = m;
    signed char* qrow = xq + (size_t)r * K;
    for (int k = lane * 8; k < K; k += 512) {
      const f32x4* p = (const f32x4*)(row + k);
      f32x4 v0 = p[0], v1 = p[1];
      unsigned b[8];
#pragma unroll
      for (int j = 0; j < 4; ++j) {
        b[j] = (unsigned)((int)rintf(fminf(fmaxf(v0[j] * si, -127.f), 127.f))) & 255u;
        b[4 + j] = (unsigned)((int)rintf(fminf(fmaxf(v1[j] * si, -127.f), 127.f))) & 255u;
      }
      uint2 o;
      o.x = b[0] | (b[1] << 8) | (b[2] << 16) | (b[3] << 24);
      o.y = b[4] | (b[5] << 8) | (b[6] << 16) | (b[7] << 24);
      *(uint2*)(qrow + k) = o;
    }
  }
}

__global__ void __launch_bounds__(256) bin_w_i8(const unsigned* __restrict__ in,
                                                signed char* __restrict__ out,
                                                int n8) {
  int i = blockIdx.x * 256 + threadIdx.x;
  const int stride = gridDim.x * 256;
  for (; i < n8; i += stride) {
    const u32x4* p = (const u32x4*)in + (size_t)i * 2;
    u32x4 v0 = p[0], v1 = p[1];
    unsigned b[8];
#pragma unroll
    for (int j = 0; j < 4; ++j) {  // sign(0)=+1: byte = w<0 ? 0xFF : 0x01
      b[j] = 1u | ((unsigned)(((int)v0[j]) >> 31) & 0xFEu);
      b[4 + j] = 1u | ((unsigned)(((int)v1[j]) >> 31) & 0xFEu);
    }
    uint2 o;
    o.x = b[0] | (b[1] << 8) | (b[2] << 16) | (b[3] << 24);
    o.y = b[4] | (b[5] << 8) | (b[6] << 16) | (b[7] << 24);
    *(uint2*)(out + (size_t)i * 8) = o;
  }
}

// ---------------- i8 GEMM: R11 verbatim (655 us measured) ----------------
// LDS (128 KiB): buf{0,1} x {A 32 KB [256 rows x 128 B], B 32 KB}.
//   row byte = row*128 + ((ch ^ (row&7))*16), ch = logical 16B chunk 0..7.
// Frag (32x32x32): lane -> row l31, 16B chunk (s<<1)|(lane>>5);
//   addr(s) = rd ^ (s<<5). Stage: dest tid*16 linear; source logical ch
//   kc2 = (tid&7)^((tid>>3)&7). Iter: [stage t+1 (8 loads)] [4 k-steps x
//   {6 ds_read_b128, 8 MFMA}] [vmcnt(0): full-iteration-old loads] [BAR].

#define WAITV0() asm volatile("s_waitcnt vmcnt(0)" ::: "memory")
#define BAR()    __builtin_amdgcn_s_barrier()
#define LDSB ((const char*)lds)

#define STAGE_I8(bufo, koff)                                                   \
  do {                                                                         \
    _Pragma("unroll") for (int g = 0; g < 4; ++g)                              \
        __builtin_amdgcn_global_load_lds(                                      \
            AS1(sA + (long)g * 64 * Kb + (koff)),                              \
            AS3((char*)lds + (bufo) + g * 8192 + tid * 16), 16, 0, 0);         \
    _Pragma("unroll") for (int g = 0; g < 4; ++g)                              \
        __builtin_amdgcn_global_load_lds(                                      \
            AS1(sB + (long)g * 64 * Kb + (koff)),                              \
            AS3((char*)lds + (bufo) + 32768 + g * 8192 + tid * 16), 16, 0, 0); \
  } while (0)

__global__ void __launch_bounds__(512, 2)
gemm_i8(const signed char* __restrict__ A, const signed char* __restrict__ B,
        const float* __restrict__ scale, const float* __restrict__ bias,
        const float* __restrict__ srow, float* __restrict__ C,
        const int M, const int N, const int K) {
  __shared__ signed char lds[131072];  // 128 KiB
  const int tid = threadIdx.x;
  const int lane = tid & 63;
  const int wv = tid >> 6;   // 0..7
  const int wm = wv >> 2;    // 0..1
  const int wn = wv & 3;     // 0..3
  const int l31 = lane & 31, l5 = lane >> 5;

  // XCD-aware swizzle (bijective: nwg % 8 == 0)
  const int mt = M >> 8, nt = N >> 8;
  const int nwg = mt * nt;
  const int orig = blockIdx.x;
  const int wg = (nwg & 7) ? orig : ((orig & 7) * (nwg >> 3) + (orig >> 3));
  const int bm = wg % mt;
  const int bn = wg / mt;
  const int rA0 = bm * 256, rB0 = bn * 256;

  // ds_read bases: row*128 + ((l5 ^ (row&7))*16); row&7 == l31&7
  const int chb = (l5 ^ (l31 & 7)) * 16;
  const int rdA = (wm * 128 + l31) * 128 + chb;
  const int rdB = 32768 + (wn * 64 + l31) * 128 + chb;

  // stage source base (inverse-swizzled)
  const int kc2 = (tid & 7) ^ ((tid >> 3) & 7);
  const long Kb = (long)K;  // bytes per row (i8)
  const signed char* sA = A + (long)(rA0 + (tid >> 3)) * Kb + kc2 * 16;
  const signed char* sB = B + (long)(rB0 + (tid >> 3)) * Kb + kc2 * 16;

  i32x16 acc[4][2] = {};
  const int NT = K >> 7;  // 32

  // prologue: tile 0 -> buf0
  STAGE_I8(0, 0);
  WAITV0();
  BAR();

  for (int t = 0; t < NT; ++t) {
    const int bufR = (t & 1) << 16;
    const int bufW = bufR ^ 65536;
    int tt = t + 1; if (tt == NT) tt = 0;  // wrapped final stage (harmless)
    STAGE_I8(bufW, (long)tt * 128);

#pragma unroll
    for (int s = 0; s < 4; ++s) {
      const int sx = s << 5;
      i32x4 a[4], b[2];
#pragma unroll
      for (int nj = 0; nj < 2; ++nj)
        b[nj] = *(const i32x4*)(LDSB + bufR + ((rdB + nj * 4096) ^ sx));
#pragma unroll
      for (int mi = 0; mi < 4; ++mi)
        a[mi] = *(const i32x4*)(LDSB + bufR + ((rdA + mi * 4096) ^ sx));
#pragma unroll
      for (int mi = 0; mi < 4; ++mi)
#pragma unroll
        for (int nj = 0; nj < 2; ++nj)
          acc[mi][nj] = __builtin_amdgcn_mfma_i32_32x32x32_i8(
              a[mi], b[nj], acc[mi][nj], 0, 0, 0);
    }

    WAITV0();  // retires tile t+1's 8 loads (issued a full iteration ago)
    BAR();     // publish buf[t+1]
  }

  // epilogue: C[m][n] = acc * (srow[m]/127 * scale) + bias[n]
  // 32x32 C/D (verified): col = lane&31, row = (r&3)+8*(r>>2)+4*(lane>>5)
  const float s127 = scale[0] * (1.0f / 127.0f);
  const int n0 = rB0 + wn * 64 + l31;
  float bb[2];
  bb[0] = bias[n0];
  bb[1] = bias[n0 + 32];
  const int m0 = rA0 + wm * 128 + 4 * l5;
#pragma unroll
  for (int mi = 0; mi < 4; ++mi) {
#pragma unroll
    for (int r = 0; r < 16; ++r) {
      const int row = m0 + mi * 32 + (r & 3) + 8 * (r >> 2);
      const float sv = srow[row] * s127;
#pragma unroll
      for (int nj = 0; nj < 2; ++nj)
        C[(size_t)row * N + n0 + nj * 32] = (float)acc[mi][nj][r] * sv + bb[nj];
    }
  }
}

// ---------------- no-workspace fallback (bf16 MFMA, in-kernel convert) ----
__device__ __forceinline__ unsigned short f2bf(float f) {
  unsigned u = __float_as_uint(f);
  u += 0x7FFFu + ((u >> 16) & 1u);
  return (unsigned short)(u >> 16);
}

__global__ void __launch_bounds__(256, 2)
gemm_fallback(const float* __restrict__ Ap, const float* __restrict__ Bp,
              const float* __restrict__ scale, const float* __restrict__ bias,
              float* __restrict__ C, const int M, const int N, const int K) {
  __shared__ unsigned short As[128 * 64];
  __shared__ unsigned short Bs[128 * 64];
  const int tid = threadIdx.x;
  const int lane = tid & 63;
  const int wv = tid >> 6;
  const int wm = wv >> 1, wn = wv & 1;
  const int bn = blockIdx.x, bm = blockIdx.y;
  const int lr = lane & 15, lk = lane >> 4;
  f32x4 acc[4][4] = {};
  const int rA0 = bm * 128, rB0 = bn * 128;

  for (int k0 = 0; k0 < K; k0 += 64) {
#pragma unroll
    for (int i = 0; i < 4; ++i) {
      const int c = i * 256 + tid;
      const int row = c >> 3, kc = c & 7;
      const f32x4* srcA = (const f32x4*)(Ap + (size_t)(rA0 + row) * K + (k0 + kc * 8));
      f32x4 v0 = srcA[0], v1 = srcA[1];
      s16x8 o;
      o[0] = (short)f2bf(v0[0]); o[1] = (short)f2bf(v0[1]);
      o[2] = (short)f2bf(v0[2]); o[3] = (short)f2bf(v0[3]);
      o[4] = (short)f2bf(v1[0]); o[5] = (short)f2bf(v1[1]);
      o[6] = (short)f2bf(v1[2]); o[7] = (short)f2bf(v1[3]);
      *(s16x8*)&As[(row * 8 + (kc ^ (row & 7))) * 8] = o;
      const u32x4* srcB =
          (const u32x4*)(Bp + (size_t)(rB0 + row) * K + (k0 + kc * 8));
      u32x4 w0 = srcB[0], w1 = srcB[1];
      s16x8 ob;
      ob[0] = (short)(0x3F80u | ((w0[0] >> 16) & 0x8000u));
      ob[1] = (short)(0x3F80u | ((w0[1] >> 16) & 0x8000u));
      ob[2] = (short)(0x3F80u | ((w0[2] >> 16) & 0x8000u));
      ob[3] = (short)(0x3F80u | ((w0[3] >> 16) & 0x8000u));
      ob[4] = (short)(0x3F80u | ((w1[0] >> 16) & 0x8000u));
      ob[5] = (short)(0x3F80u | ((w1[1] >> 16) & 0x8000u));
      ob[6] = (short)(0x3F80u | ((w1[2] >> 16) & 0x8000u));
      ob[7] = (short)(0x3F80u | ((w1[3] >> 16) & 0x8000u));
      *(s16x8*)&Bs[(row * 8 + (kc ^ (row & 7))) * 8] = ob;
    }
    __syncthreads();
#pragma unroll
    for (int ks = 0; ks < 2; ++ks) {
      s16x8 a[4], b[4];
#pragma unroll
      for (int mi = 0; mi < 4; ++mi) {
        const int row = wm * 64 + mi * 16 + lr;
        const int kc = ks * 4 + lk;
        a[mi] = *(const s16x8*)&As[(row * 8 + (kc ^ (row & 7))) * 8];
      }
#pragma unroll
      for (int ni = 0; ni < 4; ++ni) {
        const int row = wn * 64 + ni * 16 + lr;
        const int kc = ks * 4 + lk;
        b[ni] = *(const s16x8*)&Bs[(row * 8 + (kc ^ (row & 7))) * 8];
      }
#pragma unroll
      for (int mi = 0; mi < 4; ++mi)
#pragma unroll
        for (int ni = 0; ni < 4; ++ni)
          acc[mi][ni] = __builtin_amdgcn_mfma_f32_16x16x32_bf16(a[mi], b[ni],
                                                               acc[mi][ni], 0, 0, 0);
    }
    __syncthreads();
  }

  const float s = scale[0];
  const int n0 = rB0 + wn * 64 + lr;
  const int m0 = rA0 + wm * 64 + lk * 4;
  float bb[4];
#pragma unroll
  for (int ni = 0; ni < 4; ++ni) bb[ni] = bias[n0 + ni * 16];
#pragma unroll
  for (int mi = 0; mi < 4; ++mi) {
#pragma unroll
    for (int r = 0; r < 4; ++r) {
      float* crow = C + (size_t)(m0 + mi * 16 + r) * N + n0;
#pragma unroll
      for (int ni = 0; ni < 4; ++ni)
        crow[ni * 16] = acc[mi][ni][r] * s + bb[ni];
    }
  }
}

extern "C" void kernel_launch(void* const* d_in, const int* in_sizes, int n_in,
                              void* d_out, int out_size, void* d_ws, size_t ws_size,
                              hipStream_t stream) {
  const float* x = (const float*)d_in[0];
  const float* w = (const float*)d_in[1];
  const float* scale = (const float*)d_in[2];
  const float* bias = (const float*)d_in[3];
  float* out = (float*)d_out;

  const int K = 4096;
  const int M = in_sizes[0] / K;  // 8192
  const int N = in_sizes[3];      // 16384

  const size_t MK = (size_t)M * K, NK = (size_t)N * K;
  const size_t srowB = (((size_t)M * 4 + 255) / 256) * 256;  // 32 KB aligned
  const size_t need = srowB + MK + NK;  // srow + x_i8 + w_i8 (~96 MB)

  if (ws_size >= need && (M % 256) == 0 && (N % 256) == 0 && (K % 128) == 0 &&
      (K % 8) == 0 && (K / 128) >= 2) {
    float* srow = (float*)d_ws;
    signed char* xq = (signed char*)d_ws + srowB;
    signed char* wq = (signed char*)d_ws + srowB + MK;
    quant_rows<<<2048, 256, 0, stream>>>(x, xq, srow, M, K);
    bin_w_i8<<<2048, 256, 0, stream>>>((const unsigned*)w, wq, (int)(NK / 8));
    gemm_i8<<<dim3((M / 256) * (N / 256)), 512, 0, stream>>>(
        xq, wq, scale, bias, srow, out, M, N, K);
  } else {
    gemm_fallback<<<dim3(N / 128, M / 128), 256, 0, stream>>>(
        x, w, scale, bias, out, M, N, K);
  }
}